// Round 1
// baseline (1874.382 us; speedup 1.0000x reference)
//
#include <hip/hip_runtime.h>

#define NB   16
#define NPTS 32768
#define NC   64
#define RES  32
#define R3   32768        // 32^3
#define EPSV 1e-6f

// ---------------------------------------------------------------------------
// Kernel 1: per-batch mean (double accum) + max centered norm -> stats[b*4+{0,1,2}]=mean,
//           stats[b*4+3] = 2*max_norm + EPS (the divisor used by the reference)
// ---------------------------------------------------------------------------
__global__ __launch_bounds__(1024) void stats_kernel(const float* __restrict__ coords,
                                                     float* __restrict__ stats) {
    const int b = blockIdx.x;
    const int t = threadIdx.x;
    const float* cb = coords + (size_t)b * NPTS * 3;

    double sx = 0.0, sy = 0.0, sz = 0.0;
    for (int n = t; n < NPTS; n += 1024) {
        sx += (double)cb[n * 3 + 0];
        sy += (double)cb[n * 3 + 1];
        sz += (double)cb[n * 3 + 2];
    }

    __shared__ double sd[1024];
    __shared__ float  res[3];

    // reduce x
    sd[t] = sx; __syncthreads();
    for (int o = 512; o > 0; o >>= 1) { if (t < o) sd[t] += sd[t + o]; __syncthreads(); }
    if (t == 0) res[0] = (float)(sd[0] / (double)NPTS);
    __syncthreads();
    // reduce y
    sd[t] = sy; __syncthreads();
    for (int o = 512; o > 0; o >>= 1) { if (t < o) sd[t] += sd[t + o]; __syncthreads(); }
    if (t == 0) res[1] = (float)(sd[0] / (double)NPTS);
    __syncthreads();
    // reduce z
    sd[t] = sz; __syncthreads();
    for (int o = 512; o > 0; o >>= 1) { if (t < o) sd[t] += sd[t + o]; __syncthreads(); }
    if (t == 0) res[2] = (float)(sd[0] / (double)NPTS);
    __syncthreads();

    const float mx = res[0], my = res[1], mz = res[2];

    float mn = 0.0f;
    for (int n = t; n < NPTS; n += 1024) {
        float dx = cb[n * 3 + 0] - mx;
        float dy = cb[n * 3 + 1] - my;
        float dz = cb[n * 3 + 2] - mz;
        float nrm = sqrtf(dx * dx + dy * dy + dz * dz);
        mn = fmaxf(mn, nrm);
    }
    float* sf = (float*)sd;
    sf[t] = mn; __syncthreads();
    for (int o = 512; o > 0; o >>= 1) { if (t < o) sf[t] = fmaxf(sf[t], sf[t + o]); __syncthreads(); }

    if (t == 0) {
        stats[b * 4 + 0] = mx;
        stats[b * 4 + 1] = my;
        stats[b * 4 + 2] = mz;
        stats[b * 4 + 3] = sf[0] * 2.0f + EPSV;   // divisor
    }
}

// ---------------------------------------------------------------------------
// Kernel 2: one wave (64 lanes) per point; lane = channel.
//   - coalesced 256B feature load per point
//   - atomicAdd directly into transposed output layout out0[b][c][vox]
//   - lane 0 writes normalized coords + count atomic
// ---------------------------------------------------------------------------
__global__ __launch_bounds__(256) void scatter_kernel(const float* __restrict__ features,
                                                      const float* __restrict__ coords,
                                                      const float* __restrict__ stats,
                                                      float* __restrict__ out0,
                                                      float* __restrict__ nc_out,
                                                      float* __restrict__ counts) {
    const int tid  = blockIdx.x * 256 + threadIdx.x;
    const int p    = tid >> 6;          // global point id, 0..NB*NPTS-1
    const int lane = tid & 63;
    const int b    = p >> 15;           // NPTS = 32768

    const float mx = stats[b * 4 + 0];
    const float my = stats[b * 4 + 1];
    const float mz = stats[b * 4 + 2];
    const float s  = stats[b * 4 + 3];

    const float cx = coords[(size_t)p * 3 + 0];
    const float cy = coords[(size_t)p * 3 + 1];
    const float cz = coords[(size_t)p * 3 + 2];

    const float nx = (cx - mx) / s + 0.5f;
    const float ny = (cy - my) / s + 0.5f;
    const float nz = (cz - mz) / s + 0.5f;

    int vx = (int)rintf(nx * (float)(RES - 1));
    int vy = (int)rintf(ny * (float)(RES - 1));
    int vz = (int)rintf(nz * (float)(RES - 1));
    vx = min(max(vx, 0), RES - 1);
    vy = min(max(vy, 0), RES - 1);
    vz = min(max(vz, 0), RES - 1);
    const int vox = vx * (RES * RES) + vy * RES + vz;

    if (lane == 0) {
        nc_out[(size_t)p * 3 + 0] = nx;
        nc_out[(size_t)p * 3 + 1] = ny;
        nc_out[(size_t)p * 3 + 2] = nz;
        atomicAdd(counts + ((size_t)b << 15) + vox, 1.0f);
    }

    const float f = features[(size_t)p * NC + lane];
    atomicAdd(out0 + (((size_t)b * NC + lane) << 15) + vox, f);
}

// ---------------------------------------------------------------------------
// Kernel 3: out0[b][c][vox] /= max(count[b][vox], 1)  (float4 vectorized)
// ---------------------------------------------------------------------------
__global__ __launch_bounds__(256) void finalize_kernel(float* __restrict__ out0,
                                                       const float* __restrict__ counts) {
    const int i = blockIdx.x * 256 + threadIdx.x;   // index over float4, total 8388608
    const int vox4 = i & 8191;                      // 32768/4 float4 per (b,c) plane
    const int bc   = i >> 13;
    const int b    = bc >> 6;

    float4 cnt = ((const float4*)(counts + ((size_t)b << 15)))[vox4];
    float4 v   = ((float4*)out0)[i];
    v.x /= fmaxf(cnt.x, 1.0f);
    v.y /= fmaxf(cnt.y, 1.0f);
    v.z /= fmaxf(cnt.z, 1.0f);
    v.w /= fmaxf(cnt.w, 1.0f);
    ((float4*)out0)[i] = v;
}

extern "C" void kernel_launch(void* const* d_in, const int* in_sizes, int n_in,
                              void* d_out, int out_size, void* d_ws, size_t ws_size,
                              hipStream_t stream) {
    const float* features = (const float*)d_in[0];   // [16,32768,64] f32
    const float* coords   = (const float*)d_in[1];   // [16,32768,3]  f32

    float* out0   = (float*)d_out;                   // [16,64,32,32,32] = 33554432 f32
    float* nc_out = (float*)d_out + (size_t)NB * NC * R3;  // [16,32768,3]

    float* stats  = (float*)d_ws;                          // 16*4 floats
    float* counts = (float*)((char*)d_ws + 256);           // 16*32768 floats = 8 MB

    // zero the atomic accumulators
    hipMemsetAsync(out0,   0, (size_t)NB * NC * R3 * sizeof(float), stream);
    hipMemsetAsync(counts, 0, (size_t)NB * R3 * sizeof(float), stream);

    stats_kernel<<<NB, 1024, 0, stream>>>(coords, stats);

    const int total_threads = NB * NPTS * 64;        // one wave per point
    scatter_kernel<<<total_threads / 256, 256, 0, stream>>>(features, coords, stats,
                                                            out0, nc_out, counts);

    finalize_kernel<<<(NB * NC * R3 / 4) / 256, 256, 0, stream>>>(out0, counts);
}

// Round 2
// 419.861 us; speedup vs baseline: 4.4643x; 4.4643x over previous
//
#include <hip/hip_runtime.h>

#define NB   16
#define NPTS 32768
#define NC   64
#define RES  32
#define R3   32768        // 32^3
#define EPSV 1e-6f
#define SLICES 8          // stat slices per batch

// ---------------------------------------------------------------------------
// Stats pass A: per-(batch,slice) partial coordinate sums (double accum).
// Grid: NB*SLICES blocks x 256 threads.  psum[blk][3] doubles.
// ---------------------------------------------------------------------------
__global__ __launch_bounds__(256) void stats_partial_kernel(const float* __restrict__ coords,
                                                            double* __restrict__ psum) {
    const int blk = blockIdx.x;
    const int b = blk >> 3, s = blk & (SLICES - 1);
    const int cnt = NPTS / SLICES;                       // 4096
    const float* cb = coords + ((size_t)b * NPTS + (size_t)s * cnt) * 3;

    double sx = 0.0, sy = 0.0, sz = 0.0;
    for (int n = threadIdx.x; n < cnt; n += 256) {
        sx += (double)cb[n * 3 + 0];
        sy += (double)cb[n * 3 + 1];
        sz += (double)cb[n * 3 + 2];
    }
    __shared__ double sd[256];
    const int t = threadIdx.x;
    sd[t] = sx; __syncthreads();
    for (int o = 128; o > 0; o >>= 1) { if (t < o) sd[t] += sd[t + o]; __syncthreads(); }
    if (t == 0) psum[blk * 3 + 0] = sd[0];
    __syncthreads();
    sd[t] = sy; __syncthreads();
    for (int o = 128; o > 0; o >>= 1) { if (t < o) sd[t] += sd[t + o]; __syncthreads(); }
    if (t == 0) psum[blk * 3 + 1] = sd[0];
    __syncthreads();
    sd[t] = sz; __syncthreads();
    for (int o = 128; o > 0; o >>= 1) { if (t < o) sd[t] += sd[t + o]; __syncthreads(); }
    if (t == 0) psum[blk * 3 + 2] = sd[0];
}

// ---------------------------------------------------------------------------
// Stats pass B: per-(batch,slice) partial max ||c - mean||.  Every block
// redundantly reduces the 8 slice-sums for its batch (24 doubles, cheap).
// Block (b,0) thread 0 also writes the f32 means into stats.
// ---------------------------------------------------------------------------
__global__ __launch_bounds__(256) void maxnorm_partial_kernel(const float* __restrict__ coords,
                                                              const double* __restrict__ psum,
                                                              float* __restrict__ pmax,
                                                              float* __restrict__ stats) {
    const int blk = blockIdx.x;
    const int b = blk >> 3, s = blk & (SLICES - 1);
    const int cnt = NPTS / SLICES;

    double dx = 0.0, dy = 0.0, dz = 0.0;
    for (int i = 0; i < SLICES; i++) {
        dx += psum[(b * SLICES + i) * 3 + 0];
        dy += psum[(b * SLICES + i) * 3 + 1];
        dz += psum[(b * SLICES + i) * 3 + 2];
    }
    const float mx = (float)(dx / (double)NPTS);
    const float my = (float)(dy / (double)NPTS);
    const float mz = (float)(dz / (double)NPTS);

    if (s == 0 && threadIdx.x == 0) {
        stats[b * 4 + 0] = mx;
        stats[b * 4 + 1] = my;
        stats[b * 4 + 2] = mz;
    }

    const float* cb = coords + ((size_t)b * NPTS + (size_t)s * cnt) * 3;
    float mn = 0.0f;
    for (int n = threadIdx.x; n < cnt; n += 256) {
        float ax = cb[n * 3 + 0] - mx;
        float ay = cb[n * 3 + 1] - my;
        float az = cb[n * 3 + 2] - mz;
        mn = fmaxf(mn, sqrtf(ax * ax + ay * ay + az * az));
    }
    __shared__ float sf[256];
    const int t = threadIdx.x;
    sf[t] = mn; __syncthreads();
    for (int o = 128; o > 0; o >>= 1) { if (t < o) sf[t] = fmaxf(sf[t], sf[t + o]); __syncthreads(); }
    if (t == 0) pmax[blk] = sf[0];
}

// Stats pass C: final per-batch max -> divisor.
__global__ __launch_bounds__(64) void stats_final_kernel(const float* __restrict__ pmax,
                                                         float* __restrict__ stats) {
    const int b = threadIdx.x;
    if (b < NB) {
        float m = 0.0f;
        for (int i = 0; i < SLICES; i++) m = fmaxf(m, pmax[b * SLICES + i]);
        stats[b * 4 + 3] = m * 2.0f + EPSV;
    }
}

// ---------------------------------------------------------------------------
// Scatter (fast path): one wave per point; lane = channel.  Atomics into
// acc[b][vox][c] -> a point's 64 atomics land in 256 CONTIGUOUS bytes
// (4 cache lines instead of 64).  Lanes 0-2 write normalized coords.
// ---------------------------------------------------------------------------
__global__ __launch_bounds__(256) void scatter_vc_kernel(const float* __restrict__ features,
                                                         const float* __restrict__ coords,
                                                         const float* __restrict__ stats,
                                                         float* __restrict__ acc,
                                                         float* __restrict__ nc_out,
                                                         float* __restrict__ counts) {
    const int tid  = blockIdx.x * 256 + threadIdx.x;
    const int p    = tid >> 6;
    const int lane = tid & 63;
    const int b    = p >> 15;

    const float mx = stats[b * 4 + 0];
    const float my = stats[b * 4 + 1];
    const float mz = stats[b * 4 + 2];
    const float s  = stats[b * 4 + 3];

    const float cx = coords[(size_t)p * 3 + 0];
    const float cy = coords[(size_t)p * 3 + 1];
    const float cz = coords[(size_t)p * 3 + 2];

    const float nx = (cx - mx) / s + 0.5f;
    const float ny = (cy - my) / s + 0.5f;
    const float nz = (cz - mz) / s + 0.5f;

    int vx = (int)rintf(nx * (float)(RES - 1));
    int vy = (int)rintf(ny * (float)(RES - 1));
    int vz = (int)rintf(nz * (float)(RES - 1));
    vx = min(max(vx, 0), RES - 1);
    vy = min(max(vy, 0), RES - 1);
    vz = min(max(vz, 0), RES - 1);
    const int vox = vx * (RES * RES) + vy * RES + vz;

    if (lane < 3) {
        const float v = (lane == 0) ? nx : ((lane == 1) ? ny : nz);
        nc_out[(size_t)p * 3 + lane] = v;
    }
    if (lane == 0) atomicAdd(counts + ((size_t)b << 15) + vox, 1.0f);

    const float f = features[(size_t)p * NC + lane];
    atomicAdd(acc + (((size_t)((b << 15) + vox)) << 6) + lane, f);
}

// ---------------------------------------------------------------------------
// Finalize (fast path): tiled LDS transpose acc[b][vox][c] -> out0[b][c][vox],
// fused with division by max(count,1).  64x64 tile per block.
// ---------------------------------------------------------------------------
__global__ __launch_bounds__(256) void finalize_transpose_kernel(const float* __restrict__ acc,
                                                                 const float* __restrict__ counts,
                                                                 float* __restrict__ out0) {
    const int b    = blockIdx.x >> 9;        // 512 tiles per batch
    const int tile = blockIdx.x & 511;
    const int v0   = tile << 6;
    const int tid  = threadIdx.x;

    __shared__ float t[64][65];
    __shared__ float rc[64];

    if (tid < 64) rc[tid] = 1.0f / fmaxf(counts[((size_t)b << 15) + v0 + tid], 1.0f);
    __syncthreads();

    const float* a = acc + (((size_t)((b << 15) + v0)) << 6);
#pragma unroll
    for (int i = 0; i < 16; i++) {
        const int f = i * 256 + tid;
        const int vl = f >> 6, c = f & 63;
        t[vl][c] = a[f] * rc[vl];
    }
    __syncthreads();

    float* o = out0 + ((size_t)b << 21) + v0;   // b*64*32768 + v0
#pragma unroll
    for (int i = 0; i < 16; i++) {
        const int f = i * 256 + tid;
        const int c = f >> 6, vl = f & 63;
        o[((size_t)c << 15) + vl] = t[vl][c];
    }
}

// ---------------------------------------------------------------------------
// Fallback path (round-1 kernels) used only if ws_size is too small.
// ---------------------------------------------------------------------------
__global__ __launch_bounds__(256) void scatter_kernel(const float* __restrict__ features,
                                                      const float* __restrict__ coords,
                                                      const float* __restrict__ stats,
                                                      float* __restrict__ out0,
                                                      float* __restrict__ nc_out,
                                                      float* __restrict__ counts) {
    const int tid  = blockIdx.x * 256 + threadIdx.x;
    const int p    = tid >> 6;
    const int lane = tid & 63;
    const int b    = p >> 15;

    const float mx = stats[b * 4 + 0];
    const float my = stats[b * 4 + 1];
    const float mz = stats[b * 4 + 2];
    const float s  = stats[b * 4 + 3];

    const float cx = coords[(size_t)p * 3 + 0];
    const float cy = coords[(size_t)p * 3 + 1];
    const float cz = coords[(size_t)p * 3 + 2];

    const float nx = (cx - mx) / s + 0.5f;
    const float ny = (cy - my) / s + 0.5f;
    const float nz = (cz - mz) / s + 0.5f;

    int vx = (int)rintf(nx * (float)(RES - 1));
    int vy = (int)rintf(ny * (float)(RES - 1));
    int vz = (int)rintf(nz * (float)(RES - 1));
    vx = min(max(vx, 0), RES - 1);
    vy = min(max(vy, 0), RES - 1);
    vz = min(max(vz, 0), RES - 1);
    const int vox = vx * (RES * RES) + vy * RES + vz;

    if (lane < 3) {
        const float v = (lane == 0) ? nx : ((lane == 1) ? ny : nz);
        nc_out[(size_t)p * 3 + lane] = v;
    }
    if (lane == 0) atomicAdd(counts + ((size_t)b << 15) + vox, 1.0f);

    const float f = features[(size_t)p * NC + lane];
    atomicAdd(out0 + (((size_t)b * NC + lane) << 15) + vox, f);
}

__global__ __launch_bounds__(256) void finalize_kernel(float* __restrict__ out0,
                                                       const float* __restrict__ counts) {
    const int i = blockIdx.x * 256 + threadIdx.x;
    const int vox4 = i & 8191;
    const int bc   = i >> 13;
    const int b    = bc >> 6;

    float4 cnt = ((const float4*)(counts + ((size_t)b << 15)))[vox4];
    float4 v   = ((float4*)out0)[i];
    v.x /= fmaxf(cnt.x, 1.0f);
    v.y /= fmaxf(cnt.y, 1.0f);
    v.z /= fmaxf(cnt.z, 1.0f);
    v.w /= fmaxf(cnt.w, 1.0f);
    ((float4*)out0)[i] = v;
}

extern "C" void kernel_launch(void* const* d_in, const int* in_sizes, int n_in,
                              void* d_out, int out_size, void* d_ws, size_t ws_size,
                              hipStream_t stream) {
    const float* features = (const float*)d_in[0];   // [16,32768,64] f32
    const float* coords   = (const float*)d_in[1];   // [16,32768,3]  f32

    float* out0   = (float*)d_out;                               // [16,64,32,32,32]
    float* nc_out = (float*)d_out + (size_t)NB * NC * R3;        // [16,32768,3]

    // ws layout
    char* ws = (char*)d_ws;
    float*  stats  = (float*)ws;                                 // 256 B
    double* psum   = (double*)(ws + 256);                        // 128*3 doubles = 3 KB
    float*  pmax   = (float*)(ws + 4096);                        // 512 B
    float*  counts = (float*)(ws + 8192);                        // 2 MB
    float*  acc    = (float*)(ws + 8192 + (size_t)NB * R3 * 4);  // 128 MB

    const size_t counts_bytes = (size_t)NB * R3 * 4;
    const size_t acc_bytes    = (size_t)NB * R3 * NC * 4;
    const size_t need         = 8192 + counts_bytes + acc_bytes;

    // stats (both paths)
    stats_partial_kernel<<<NB * SLICES, 256, 0, stream>>>(coords, psum);
    maxnorm_partial_kernel<<<NB * SLICES, 256, 0, stream>>>(coords, psum, pmax, stats);
    stats_final_kernel<<<1, 64, 0, stream>>>(pmax, stats);

    const int scatter_blocks = (NB * NPTS * 64) / 256;

    if (ws_size >= need) {
        // fast path: [b][vox][c] accumulator in ws, transpose-finalize
        hipMemsetAsync(counts, 0, counts_bytes + acc_bytes, stream);  // contiguous
        scatter_vc_kernel<<<scatter_blocks, 256, 0, stream>>>(features, coords, stats,
                                                              acc, nc_out, counts);
        finalize_transpose_kernel<<<NB * 512, 256, 0, stream>>>(acc, counts, out0);
    } else {
        // fallback: round-1 path
        hipMemsetAsync(out0,   0, (size_t)NB * NC * R3 * 4, stream);
        hipMemsetAsync(counts, 0, counts_bytes, stream);
        scatter_kernel<<<scatter_blocks, 256, 0, stream>>>(features, coords, stats,
                                                           out0, nc_out, counts);
        finalize_kernel<<<(NB * NC * R3 / 4) / 256, 256, 0, stream>>>(out0, counts);
    }
}